// Round 4
// baseline (13771.712 us; speedup 1.0000x reference)
//
#include <hip/hip_runtime.h>
#include <math.h>

// ---------------------------------------------------------------------------
// Problem constants
// ---------------------------------------------------------------------------
#define ET 32          // edges per block
#define EPW 8          // edges per wave
#define NODE_DIM 240
#define NODE_PAD 244   // padded LDS row stride (bank-conflict fix for 2/4-edge groups)
#define SW_FLOATS 3072 // 12KB W-staging buffer

// path tables: PATHS = [(0,0,0),(1,1,0),(2,2,0),(0,1,1),(1,0,1),(1,2,1),
//                       (2,1,1),(0,2,2),(2,0,2),(1,1,2),(2,2,2)]
// tp_w offsets (floats):
//   0,16384,24576,28672,36864,40960,45056,47104,51200,52224,54272  (total 55296)
// w3j offsets: 0,1,10,35,44,53,98,143,168,193,238 (total 363)

// ---------------------------------------------------------------------------
// Wigner-3j init kernel (exact port of the reference construction)
// ---------------------------------------------------------------------------
struct cplx { double re, im; };
__device__ inline cplx cmul(cplx a, cplx b) {
    return { a.re*b.re - a.im*b.im, a.re*b.im + a.im*b.re };
}

__device__ double dfact(int n) { double r = 1.0; for (int i = 2; i <= n; ++i) r *= i; return r; }

__device__ double su2_cg(int j1, int m1, int j2, int m2, int j3, int m3) {
    if (m3 != m1 + m2) return 0.0;
    int vmin = max(max(-j1 + j2 + m3, -j1 + m1), 0);
    int vmax = min(min(j2 + j3 + m1, j3 - j1 + j2), j3 + m3);
    double C = sqrt((2.0*j3 + 1.0) * dfact(j3 + j1 - j2) * dfact(j3 - j1 + j2) * dfact(j1 + j2 - j3)
                    * dfact(j3 + m3) * dfact(j3 - m3)
                    / (dfact(j1 + j2 + j3 + 1) * dfact(j1 - m1) * dfact(j1 + m1)
                       * dfact(j2 - m2) * dfact(j2 + m2)));
    double S = 0.0;
    for (int v = vmin; v <= vmax; ++v) {
        double sgn = ((v + j2 + m2) & 1) ? -1.0 : 1.0;
        S += sgn * dfact(j2 + j3 + m1 - v) * dfact(j1 - m1 + v)
             / (dfact(v) * dfact(j3 - j1 + j2 - v) * dfact(j3 + m3 - v) * dfact(v + j1 - j2 - m3));
    }
    return C * S;
}

// element (a,b) of (-i)^l * q  where q is the real->complex change of basis
__device__ cplx rtc(int l, int a, int b) {
    double re = 0.0, im = 0.0;
    const double inv_s2 = 0.70710678118654752440;
    int m = a - l;
    if (m < 0) {
        if (b == l - m)      re = inv_s2;        // col l+|m|
        else if (b == l + m) im = -inv_s2;       // col l-|m|
    } else if (m == 0) {
        if (b == l) re = 1.0;
    } else {
        double s = (m & 1) ? -1.0 : 1.0;
        if (b == l + m)      re = s * inv_s2;
        else if (b == l - m) im = s * inv_s2;
    }
    if (l == 1) { double t = re; re = im; im = -t; }     // * (-i)
    else if (l == 2) { re = -re; im = -im; }             // * (-1)
    return { re, im };
}

__global__ void w3j_init(float* __restrict__ out) {
    __shared__ double sRe[363], sIm[363];
    __shared__ double sNorm[11];
    __shared__ int    sUse[11];
    const int L1A[11] = {0,1,2,0,1,1,2,0,2,1,2};
    const int L2A[11] = {0,1,2,1,0,2,1,2,0,1,2};
    const int L3A[11] = {0,0,0,1,1,1,1,2,2,2,2};
    const int OFF[12] = {0,1,10,35,44,53,98,143,168,193,238,363};
    int t = threadIdx.x;
    if (t < 363) {
        int p = 0;
        while (p < 10 && t >= OFF[p+1]) ++p;
        int rel = t - OFF[p];
        int a1 = L1A[p], a2 = L2A[p], a3 = L3A[p];
        int n1 = 2*a1 + 1, n2 = 2*a2 + 1, n3 = 2*a3 + 1;
        int jj = rel / (n2*n3), ll = (rel / n3) % n2, mm = rel % n3;
        double cr = 0.0, ci = 0.0;
        for (int i = 0; i < n1; ++i)
            for (int k = 0; k < n2; ++k)
                for (int n = 0; n < n3; ++n) {
                    double c = su2_cg(a1, i - a1, a2, k - a2, a3, n - a3);
                    if (c == 0.0) continue;
                    cplx q1 = rtc(a1, i, jj);
                    cplx q2 = rtc(a2, k, ll);
                    cplx q3 = rtc(a3, n, mm); q3.im = -q3.im;   // conj
                    cplx pr = cmul(cmul(q1, q2), q3);
                    cr += pr.re * c; ci += pr.im * c;
                }
        sRe[t] = cr; sIm[t] = ci;
    }
    __syncthreads();
    if (t < 11) {
        double nr = 0.0, ni = 0.0;
        for (int e = OFF[t]; e < OFF[t+1]; ++e) { nr += sRe[e]*sRe[e]; ni += sIm[e]*sIm[e]; }
        int use_im = (sqrt(nr) < 1e-8) ? 1 : 0;
        sUse[t] = use_im;
        sNorm[t] = sqrt(use_im ? ni : nr);
    }
    __syncthreads();
    if (t < 363) {
        int p = 0;
        while (p < 10 && t >= OFF[p+1]) ++p;
        out[t] = (float)((sUse[p] ? sIm[t] : sRe[t]) / sNorm[p]);
    }
}

// ---------------------------------------------------------------------------
// Main kernel
// ---------------------------------------------------------------------------
// one path, templated so all small arrays stay in registers
template<int l1, int l2, int l3>
__device__ void do_path(int tid, int woff, int cgoff,
                        const float* __restrict__ tp_w,
                        float* sW, float (*sAcc)[NODE_DIM],
                        const float (*sWl)[12], const float (*sY)[8],
                        const float (*sNode)[NODE_PAD], const float* sW3)
{
    constexpr int U  = (l1 == 0) ? 64 : (l1 == 1) ? 32 : 16;
    constexpr int WD = (l3 == 0) ? 64 : (l3 == 1) ? 32 : 16;
    constexpr int NI = 2*l1 + 1, NJ = 2*l2 + 1, NK = 2*l3 + 1;
    constexpr int CAP = SW_FLOATS / (4*WD);          // u-capacity of sW
    constexpr int UC  = (CAP < U) ? CAP : U;
    constexpr int NE = 64 / WD;        // lane groups (edges side-by-side in a wave)
    constexpr int P  = EPW / (NE * 2); // passes; 2 edges per lane per pass
    constexpr int NODE_OFF = (l1 == 0) ? 0 : (l1 == 1) ? 64 : 160;
    constexpr int ACC_OFF  = (l3 == 0) ? 0 : (l3 == 1) ? 64 : 160;

    int wave = tid >> 6, lane = tid & 63;
    int g = lane / WD, w = lane % WD;

    for (int u0 = 0; u0 < U; u0 += UC) {
        int uc = (U - u0 < UC) ? (U - u0) : UC;
        __syncthreads();
        // stage W chunk to LDS in [u][w][v] order; each thread gathers the 4
        // v-values of one (u,w) (coalesced global reads per v) and writes one
        // b128 (consecutive lanes -> consecutive 16B -> conflict-free).
        for (int idx = tid; idx < uc*WD; idx += 256) {
            int u_rel = idx / WD;
            int ww    = idx % WD;
            int gbase = woff + (u0 + u_rel)*(4*WD) + ww;
            float4 t;
            t.x = tp_w[gbase + 0*WD];
            t.y = tp_w[gbase + 1*WD];
            t.z = tp_w[gbase + 2*WD];
            t.w = tp_w[gbase + 3*WD];
            *reinterpret_cast<float4*>(&sW[idx*4]) = t;
        }
        __syncthreads();

        for (int p = 0; p < P; ++p) {
            int elBase = wave*EPW + (p*NE + g)*2;
            float wlv[2][4];
            float cy[2][NI][NK];
            float ak[2][NK];
            const float* nrow[2];
            #pragma unroll
            for (int jj = 0; jj < 2; ++jj) {
                int el = elBase + jj;
                #pragma unroll
                for (int v = 0; v < 4; ++v) wlv[jj][v] = sWl[el][l2*4 + v];
                #pragma unroll
                for (int i = 0; i < NI; ++i)
                    #pragma unroll
                    for (int k = 0; k < NK; ++k) cy[jj][i][k] = 0.0f;
                #pragma unroll
                for (int j = 0; j < NJ; ++j) {
                    float yj = (l2 == 0) ? 1.0f : (l2 == 1 ? sY[el][j] : sY[el][3 + j]);
                    #pragma unroll
                    for (int i = 0; i < NI; ++i)
                        #pragma unroll
                        for (int k = 0; k < NK; ++k)
                            cy[jj][i][k] += sW3[cgoff + (i*NJ + j)*NK + k] * yj;
                }
                #pragma unroll
                for (int k = 0; k < NK; ++k) ak[jj][k] = 0.0f;
                nrow[jj] = &sNode[el][NODE_OFF];
            }
            for (int ur = 0; ur < uc; ++ur) {
                int u = u0 + ur;
                float4 wv = *reinterpret_cast<const float4*>(&sW[(ur*WD + w)*4]);
                #pragma unroll
                for (int jj = 0; jj < 2; ++jj) {
                    float a = wv.x*wlv[jj][0] + wv.y*wlv[jj][1] + wv.z*wlv[jj][2] + wv.w*wlv[jj][3];
                    #pragma unroll
                    for (int i = 0; i < NI; ++i) {
                        float an = a * nrow[jj][u*NI + i];
                        #pragma unroll
                        for (int k = 0; k < NK; ++k) ak[jj][k] += an * cy[jj][i][k];
                    }
                }
            }
            #pragma unroll
            for (int jj = 0; jj < 2; ++jj) {
                int el = elBase + jj;
                #pragma unroll
                for (int k = 0; k < NK; ++k) sAcc[el][ACC_OFF + w*NK + k] += ak[jj][k];
            }
        }
    }
}

__global__ __launch_bounds__(256, 2)
void edge_main(const float* __restrict__ node_feat,
               const int*   __restrict__ edge_src,
               const float* __restrict__ edge_vec,
               const float* __restrict__ maskp,
               const float* __restrict__ mlp_w1, const float* __restrict__ mlp_b1,
               const float* __restrict__ mlp_w2, const float* __restrict__ mlp_b2,
               const float* __restrict__ tp_w,
               const float* __restrict__ w3j,
               float* __restrict__ out)
{
    __shared__ float sW[SW_FLOATS];          // 12KB: W staging (also phase-0 scratch)
    __shared__ float sNode[ET][NODE_PAD];    // 30.5KB: gathered node rows
    __shared__ float sAcc[ET][NODE_DIM];     // 30KB: full 240-ch accumulator per edge
    __shared__ float sWl[ET][12];
    __shared__ float sY[ET][8];
    __shared__ float sW3[364];
    __shared__ float sR[ET];
    __shared__ float sRb2[ET];
    __shared__ float sMask[ET];
    __shared__ int   sSrc[ET];

    // phase-0 scratch aliases onto sW (used & done before any W staging)
    float (*sRbf)[32] = (float(*)[32])sW;            // 1024 floats
    float (*sH)[32]   = (float(*)[32])(sW + 1024);   // 1024 floats

    int tid = threadIdx.x;
    long eg0 = (long)blockIdx.x * ET;

    // ---- phase 0a: per-edge geometry -------------------------------------
    if (tid < ET) {
        long eg = eg0 + tid;
        float vx = edge_vec[eg*3 + 0], vy = edge_vec[eg*3 + 1], vz = edge_vec[eg*3 + 2];
        float rn = sqrtf(vx*vx + vy*vy + vz*vz);
        float r  = fmaxf(rn, 1e-12f);
        float inv = 1.0f / r;
        float x = vx*inv, y = vy*inv, z = vz*inv;
        sR[tid] = r;
        float rb = 0.5f * (cosf(r * 3.14159265358979323846f / 5.0f) + 1.0f);
        sRb2[tid] = (r < 5.0f) ? rb*rb : 0.0f;
        sMask[tid] = maskp[eg];
        sSrc[tid]  = edge_src[eg];
        const float s3 = sqrtf(3.0f), s5 = sqrtf(5.0f), s15 = sqrtf(15.0f);
        sY[tid][0] = s3*x; sY[tid][1] = s3*y; sY[tid][2] = s3*z;
        sY[tid][3] = s15*x*z;
        sY[tid][4] = s15*x*y;
        sY[tid][5] = s5*(y*y - 0.5f*(x*x + z*z));
        sY[tid][6] = s15*y*z;
        sY[tid][7] = 0.5f*s15*(z*z - x*x);
    }
    // all 363 w3j entries (grid-stride: block has only 256 threads)
    for (int t = tid; t < 363; t += 256) sW3[t] = w3j[t];
    // zero the full accumulator once
    for (int idx = tid; idx < ET*NODE_DIM; idx += 256) ((float*)sAcc)[idx] = 0.0f;
    __syncthreads();

    // ---- phase 0b: gather node rows (coalesced float4) + radial basis ----
    for (int idx = tid; idx < ET*60; idx += 256) {
        int e = idx / 60, q = idx - e*60;
        const float4 v = *reinterpret_cast<const float4*>(node_feat + (long)sSrc[e]*NODE_DIM + q*4);
        *reinterpret_cast<float4*>(&sNode[e][q*4]) = v;
    }
    {
        float em5  = expf(-5.0f);
        float step = (1.0f - em5) / 31.0f;
        float beta = 256.0f / ((1.0f - em5) * (1.0f - em5));
        for (int idx = tid; idx < ET*32; idx += 256) {
            int e = idx >> 5, j = idx & 31;
            float mean = em5 + step * j;
            float d = expf(-sR[e]) - mean;
            sRbf[e][j] = sRb2[e] * expf(-beta * d * d);
        }
    }
    __syncthreads();

    // ---- phase 0c: per-l MLP -> edge weights wl --------------------------
    for (int l = 0; l < 3; ++l) {
        for (int idx = tid; idx < ET*32; idx += 256) {
            int e = idx >> 5, j = idx & 31;
            float zacc = mlp_b1[l*32 + j];
            #pragma unroll 8
            for (int rr = 0; rr < 32; ++rr) zacc += sRbf[e][rr] * mlp_w1[(l*32 + rr)*32 + j];
            sH[e][j] = zacc / (1.0f + expf(-zacc));   // silu
        }
        __syncthreads();
        for (int idx = tid; idx < ET*4; idx += 256) {
            int e = idx >> 2, v = idx & 3;
            float zacc = mlp_b2[l*4 + v];
            #pragma unroll 8
            for (int j = 0; j < 32; ++j) zacc += sH[e][j] * mlp_w2[(l*32 + j)*4 + v];
            sWl[e][l*4 + v] = zacc;
        }
        __syncthreads();
    }

    // ---- all 11 paths, accumulating into sAcc[e][0..239] -----------------
    do_path<0,0,0>(tid,     0,   0, tp_w, sW, sAcc, sWl, sY, sNode, sW3);
    do_path<1,1,0>(tid, 16384,   1, tp_w, sW, sAcc, sWl, sY, sNode, sW3);
    do_path<2,2,0>(tid, 24576,  10, tp_w, sW, sAcc, sWl, sY, sNode, sW3);
    do_path<0,1,1>(tid, 28672,  35, tp_w, sW, sAcc, sWl, sY, sNode, sW3);
    do_path<1,0,1>(tid, 36864,  44, tp_w, sW, sAcc, sWl, sY, sNode, sW3);
    do_path<1,2,1>(tid, 40960,  53, tp_w, sW, sAcc, sWl, sY, sNode, sW3);
    do_path<2,1,1>(tid, 45056,  98, tp_w, sW, sAcc, sWl, sY, sNode, sW3);
    do_path<0,2,2>(tid, 47104, 143, tp_w, sW, sAcc, sWl, sY, sNode, sW3);
    do_path<2,0,2>(tid, 51200, 168, tp_w, sW, sAcc, sWl, sY, sNode, sW3);
    do_path<1,1,2>(tid, 52224, 193, tp_w, sW, sAcc, sWl, sY, sNode, sW3);
    do_path<2,2,2>(tid, 54272, 238, tp_w, sW, sAcc, sWl, sY, sNode, sW3);
    __syncthreads();

    // ---- single contiguous output pass (fully coalesced float4 stream) ---
    {
        const float a0 = 1.0f / sqrtf(448.0f);   // l3=0, channels [0,64)
        const float a1 = 1.0f / 24.0f;           // l3=1, channels [64,160)
        const float a2 = 1.0f / sqrtf(512.0f);   // l3=2, channels [160,240)
        for (int idx = tid; idx < ET*60; idx += 256) {
            int e = idx / 60, q = idx - e*60;    // q indexes float4s within a row
            float al = (q < 16) ? a0 : (q < 40) ? a1 : a2;
            float m  = al * sMask[e];
            float4 v = *reinterpret_cast<const float4*>(&sAcc[e][q*4]);
            v.x *= m; v.y *= m; v.z *= m; v.w *= m;
            *reinterpret_cast<float4*>(out + eg0*NODE_DIM + (long)idx*4) = v;
        }
    }
}

// ---------------------------------------------------------------------------
// launch
// ---------------------------------------------------------------------------
extern "C" void kernel_launch(void* const* d_in, const int* in_sizes, int n_in,
                              void* d_out, int out_size, void* d_ws, size_t ws_size,
                              hipStream_t stream)
{
    const float* node_feat = (const float*)d_in[0];
    const int*   edge_idx  = (const int*)  d_in[1];
    const float* edge_vec  = (const float*)d_in[2];
    const float* maskp     = (const float*)d_in[3];
    const float* mlp_w1    = (const float*)d_in[4];
    const float* mlp_b1    = (const float*)d_in[5];
    const float* mlp_w2    = (const float*)d_in[6];
    const float* mlp_b2    = (const float*)d_in[7];
    const float* tp_w      = (const float*)d_in[8];
    float* out = (float*)d_out;
    float* w3j = (float*)d_ws;

    int E = in_sizes[3];                 // = N_EDGES = 800000 (divisible by ET)
    const int* edge_src = edge_idx;      // row 0 of (2, E)

    hipLaunchKernelGGL(w3j_init, dim3(1), dim3(512), 0, stream, w3j);
    hipLaunchKernelGGL(edge_main, dim3(E / ET), dim3(256), 0, stream,
                       node_feat, edge_src, edge_vec, maskp,
                       mlp_w1, mlp_b1, mlp_w2, mlp_b2, tp_w, w3j, out);
}

// Round 5
// 3707.998 us; speedup vs baseline: 3.7141x; 3.7141x over previous
//
#include <hip/hip_runtime.h>
#include <math.h>

// ---------------------------------------------------------------------------
// Problem constants
// ---------------------------------------------------------------------------
#define TE 32          // edges per block
#define NODE_DIM 240
#define APAD 72        // f16 row stride of A_lds (144B: 8/16B aligned, 2-way banks)
#define WPAD 72        // f16 row stride of W_lds

typedef _Float16 f16;
typedef f16 f16x2 __attribute__((ext_vector_type(2)));
typedef f16 f16x4 __attribute__((ext_vector_type(4)));
typedef f16 f16x8 __attribute__((ext_vector_type(8)));
typedef float f32x4 __attribute__((ext_vector_type(4)));

// path tables: PATHS = [(0,0,0),(1,1,0),(2,2,0),(0,1,1),(1,0,1),(1,2,1),
//                       (2,1,1),(0,2,2),(2,0,2),(1,1,2),(2,2,2)]
// tp_w offsets: 0,16384,24576,28672,36864,40960,45056,47104,51200,52224,54272
// w3j offsets:  0,1,10,35,44,53,98,143,168,193,238 (total 363)

// ---------------------------------------------------------------------------
// Wigner-3j init kernel (exact port of the reference construction)
// ---------------------------------------------------------------------------
struct cplx { double re, im; };
__device__ inline cplx cmul(cplx a, cplx b) {
    return { a.re*b.re - a.im*b.im, a.re*b.im + a.im*b.re };
}

__device__ double dfact(int n) { double r = 1.0; for (int i = 2; i <= n; ++i) r *= i; return r; }

__device__ double su2_cg(int j1, int m1, int j2, int m2, int j3, int m3) {
    if (m3 != m1 + m2) return 0.0;
    int vmin = max(max(-j1 + j2 + m3, -j1 + m1), 0);
    int vmax = min(min(j2 + j3 + m1, j3 - j1 + j2), j3 + m3);
    double C = sqrt((2.0*j3 + 1.0) * dfact(j3 + j1 - j2) * dfact(j3 - j1 + j2) * dfact(j1 + j2 - j3)
                    * dfact(j3 + m3) * dfact(j3 - m3)
                    / (dfact(j1 + j2 + j3 + 1) * dfact(j1 - m1) * dfact(j1 + m1)
                       * dfact(j2 - m2) * dfact(j2 + m2)));
    double S = 0.0;
    for (int v = vmin; v <= vmax; ++v) {
        double sgn = ((v + j2 + m2) & 1) ? -1.0 : 1.0;
        S += sgn * dfact(j2 + j3 + m1 - v) * dfact(j1 - m1 + v)
             / (dfact(v) * dfact(j3 - j1 + j2 - v) * dfact(j3 + m3 - v) * dfact(v + j1 - j2 - m3));
    }
    return C * S;
}

__device__ cplx rtc(int l, int a, int b) {
    double re = 0.0, im = 0.0;
    const double inv_s2 = 0.70710678118654752440;
    int m = a - l;
    if (m < 0) {
        if (b == l - m)      re = inv_s2;
        else if (b == l + m) im = -inv_s2;
    } else if (m == 0) {
        if (b == l) re = 1.0;
    } else {
        double s = (m & 1) ? -1.0 : 1.0;
        if (b == l + m)      re = s * inv_s2;
        else if (b == l - m) im = s * inv_s2;
    }
    if (l == 1) { double t = re; re = im; im = -t; }
    else if (l == 2) { re = -re; im = -im; }
    return { re, im };
}

__global__ void w3j_init(float* __restrict__ out) {
    __shared__ double sRe[363], sIm[363];
    __shared__ double sNorm[11];
    __shared__ int    sUse[11];
    const int L1A[11] = {0,1,2,0,1,1,2,0,2,1,2};
    const int L2A[11] = {0,1,2,1,0,2,1,2,0,1,2};
    const int L3A[11] = {0,0,0,1,1,1,1,2,2,2,2};
    const int OFF[12] = {0,1,10,35,44,53,98,143,168,193,238,363};
    int t = threadIdx.x;
    if (t < 363) {
        int p = 0;
        while (p < 10 && t >= OFF[p+1]) ++p;
        int rel = t - OFF[p];
        int a1 = L1A[p], a2 = L2A[p], a3 = L3A[p];
        int n1 = 2*a1 + 1, n2 = 2*a2 + 1, n3 = 2*a3 + 1;
        int jj = rel / (n2*n3), ll = (rel / n3) % n2, mm = rel % n3;
        double cr = 0.0, ci = 0.0;
        for (int i = 0; i < n1; ++i)
            for (int k = 0; k < n2; ++k)
                for (int n = 0; n < n3; ++n) {
                    double c = su2_cg(a1, i - a1, a2, k - a2, a3, n - a3);
                    if (c == 0.0) continue;
                    cplx q1 = rtc(a1, i, jj);
                    cplx q2 = rtc(a2, k, ll);
                    cplx q3 = rtc(a3, n, mm); q3.im = -q3.im;
                    cplx pr = cmul(cmul(q1, q2), q3);
                    cr += pr.re * c; ci += pr.im * c;
                }
        sRe[t] = cr; sIm[t] = ci;
    }
    __syncthreads();
    if (t < 11) {
        double nr = 0.0, ni = 0.0;
        for (int e = OFF[t]; e < OFF[t+1]; ++e) { nr += sRe[e]*sRe[e]; ni += sIm[e]*sIm[e]; }
        int use_im = (sqrt(nr) < 1e-8) ? 1 : 0;
        sUse[t] = use_im;
        sNorm[t] = sqrt(use_im ? ni : nr);
    }
    __syncthreads();
    if (t < 363) {
        int p = 0;
        while (p < 10 && t >= OFF[p+1]) ++p;
        out[t] = (float)((sUse[p] ? sIm[t] : sRe[t]) / sNorm[p]);
    }
}

// ---------------------------------------------------------------------------
// One path as a shared-weight GEMM on fp16 MFMA.
// A[(kk*TE+e), (u,v)] = (sum_i n[e,u,i] * cy[e,i,kk]) * wl[e,v]
// W[(u,v), w] = tp_w slice (already (u,v)-major x w row-major)
// acc (per wave task (mt,nt)) accumulates across K-chunks AND paths of a group.
// ---------------------------------------------------------------------------
template<int l1, int l2, int l3>
__device__ __forceinline__ void path_mfma(
    int tid, int woff, int cgoff,
    const float* __restrict__ tp_w,
    f16* A_lds, f16* W_lds, float* cy_lds,
    const f16* sN16, const float (*sY)[8], const float* sW3,
    const f16x2 (*sWlPk)[6],
    f32x4 (&acc)[3])
{
    constexpr int U  = (l1 == 0) ? 64 : (l1 == 1) ? 32 : 16;
    constexpr int N  = (l3 == 0) ? 64 : (l3 == 1) ? 32 : 16;   // w-dim of path
    constexpr int NI = 2*l1 + 1, NJ = 2*l2 + 1, NK = 2*l3 + 1;
    constexpr int M  = NK * TE;                // GEMM rows: row = kk*TE + e
    constexpr int NODE_OFF = (l1 == 0) ? 0 : (l1 == 1) ? 64 : 160;
    constexpr int NCH = U / 16;                // K-chunks of 64 (16 u's x 4 v)
    constexpr int NT  = N / 16;
    constexpr int NTASKS = (M / 16) * NT;

    int wv = tid >> 6;
    int ln = tid & 15, qt = (tid & 63) >> 4;

    // phase a: cy[e][i][kk] = sum_j Y[e,j] * C[i,j,kk]
    for (int idx = tid; idx < TE*NI*NK; idx += 256) {
        int e = idx / (NI*NK), rem = idx - e*(NI*NK);
        int i = rem / NK, kk = rem - i*NK;
        float c = 0.f;
        #pragma unroll
        for (int j = 0; j < NJ; ++j) {
            float yj = (l2 == 0) ? 1.f : ((l2 == 1) ? sY[e][j] : sY[e][3 + j]);
            c += sW3[cgoff + (i*NJ + j)*NK + kk] * yj;
        }
        cy_lds[idx] = c;
    }
    __syncthreads();

    for (int ch = 0; ch < NCH; ++ch) {
        int u0 = ch * 16;
        // --- stage W chunk (transposed to [n][k], f16) ---
        for (int idx = tid; idx < N*64; idx += 256) {
            int kl = idx / N, n = idx - kl*N;            // n fastest -> coalesced
            W_lds[n*WPAD + kl] = (f16)tp_w[woff + (u0*4 + kl)*N + n];
        }
        // --- build A chunk [M][64] f16 ---
        for (int idx = tid; idx < M*16; idx += 256) {
            int row = idx >> 4, ur = idx & 15;
            int kk = row >> 5, e = row & 31;             // row = kk*32 + e
            float b = 0.f;
            #pragma unroll
            for (int i = 0; i < NI; ++i)
                b += (float)sN16[e*240 + NODE_OFF + (u0 + ur)*NI + i]
                     * cy_lds[(e*NI + i)*NK + kk];
            f16 bh = (f16)b;
            f16x2 bb = {bh, bh};
            f16x2 a01 = bb * sWlPk[e][l2*2 + 0];
            f16x2 a23 = bb * sWlPk[e][l2*2 + 1];
            f16x4 av = {a01[0], a01[1], a23[0], a23[1]};
            *(f16x4*)&A_lds[row*APAD + ur*4] = av;       // 8B-aligned write
        }
        __syncthreads();
        // --- MFMA: wave tasks (mt,nt), 2 K-steps of 32 ---
        #pragma unroll
        for (int t = 0; t < 3; ++t) {
            int task = t*4 + wv;
            if (task < NTASKS) {
                int mt = task / NT, nt = task - mt*NT;
                #pragma unroll
                for (int ks = 0; ks < 2; ++ks) {
                    f16x8 af = *(const f16x8*)&A_lds[(mt*16 + ln)*APAD + ks*32 + qt*8];
                    f16x8 wf = *(const f16x8*)&W_lds[(nt*16 + ln)*WPAD + ks*32 + qt*8];
                    acc[t] = __builtin_amdgcn_mfma_f32_16x16x32_f16(af, wf, acc[t], 0, 0, 0);
                }
            }
        }
        __syncthreads();
    }
}

// write a group's accumulators into the f16 staging tile
// D layout (m89-verified): col = lane&15, row = 4*(lane>>4) + reg
template<int NK, int NT, int NTASKS, int OFF>
__device__ __forceinline__ void store_group(int tid, const f32x4 (&acc)[3], f16* sAcc16)
{
    int wv = tid >> 6;
    int ln = tid & 15, qt = (tid & 63) >> 4;
    #pragma unroll
    for (int t = 0; t < 3; ++t) {
        int task = t*4 + wv;
        if (task < NTASKS) {
            int mt = task / NT, nt = task - mt*NT;
            int kk = mt >> 1;
            int e0 = (mt & 1) * 16;
            #pragma unroll
            for (int r = 0; r < 4; ++r) {
                int e = e0 + qt*4 + r;
                sAcc16[e*240 + OFF + (nt*16 + ln)*NK + kk] = (f16)acc[t][r];
            }
        }
    }
}

__global__ __launch_bounds__(256, 2)
void edge_main(const float* __restrict__ node_feat,
               const int*   __restrict__ edge_src,
               const float* __restrict__ edge_vec,
               const float* __restrict__ maskp,
               const float* __restrict__ mlp_w1, const float* __restrict__ mlp_b1,
               const float* __restrict__ mlp_w2, const float* __restrict__ mlp_b2,
               const float* __restrict__ tp_w,
               const float* __restrict__ w3j,
               float* __restrict__ out)
{
    __shared__ __align__(16) f16 sN16[TE*240];      // 15.4KB node rows (f16)
    __shared__ __align__(16) f16 sAcc16[TE*240];    // 15.4KB result staging (f16)
    __shared__ __align__(16) f16 A_lds[160*APAD];   // 23.0KB A chunk
    __shared__ __align__(16) f16 W_lds[64*WPAD];    // 9.2KB  W chunk
    __shared__ float cy_lds[800];                   // 3.2KB
    __shared__ float sW3[364];
    __shared__ float sY[TE][8];
    __shared__ float sWl[TE][12];
    __shared__ f16x2 sWlPk[TE][6];
    __shared__ float sR[TE];
    __shared__ float sRb2[TE];
    __shared__ float sMask[TE];
    __shared__ int   sSrc[TE];

    // phase-0 MLP scratch aliases onto A_lds (used & done before any A build)
    float* sRbf = (float*)A_lds;            // [TE][32]
    float* sH   = sRbf + TE*32;             // [TE][32]

    int tid = threadIdx.x;
    long eg0 = (long)blockIdx.x * TE;

    // ---- phase 0a: per-edge geometry -------------------------------------
    if (tid < TE) {
        long eg = eg0 + tid;
        float vx = edge_vec[eg*3 + 0], vy = edge_vec[eg*3 + 1], vz = edge_vec[eg*3 + 2];
        float rn = sqrtf(vx*vx + vy*vy + vz*vz);
        float r  = fmaxf(rn, 1e-12f);
        float inv = 1.0f / r;
        float x = vx*inv, y = vy*inv, z = vz*inv;
        sR[tid] = r;
        float rb = 0.5f * (cosf(r * 3.14159265358979323846f / 5.0f) + 1.0f);
        sRb2[tid] = (r < 5.0f) ? rb*rb : 0.0f;
        sMask[tid] = maskp[eg];
        sSrc[tid]  = edge_src[eg];
        const float s3 = sqrtf(3.0f), s5 = sqrtf(5.0f), s15 = sqrtf(15.0f);
        sY[tid][0] = s3*x; sY[tid][1] = s3*y; sY[tid][2] = s3*z;
        sY[tid][3] = s15*x*z;
        sY[tid][4] = s15*x*y;
        sY[tid][5] = s5*(y*y - 0.5f*(x*x + z*z));
        sY[tid][6] = s15*y*z;
        sY[tid][7] = 0.5f*s15*(z*z - x*x);
    }
    for (int t = tid; t < 363; t += 256) sW3[t] = w3j[t];   // grid-stride (363 > 256)
    __syncthreads();

    // ---- phase 0b: gather node rows (f32 float4 -> f16 LDS) + RBF --------
    for (int idx = tid; idx < TE*60; idx += 256) {
        int e = idx / 60, q = idx - e*60;
        f32x4 v = *(const f32x4*)(node_feat + (long)sSrc[e]*NODE_DIM + q*4);
        f16x4 h = {(f16)v.x, (f16)v.y, (f16)v.z, (f16)v.w};
        *(f16x4*)&sN16[e*240 + q*4] = h;
    }
    {
        float em5  = expf(-5.0f);
        float step = (1.0f - em5) / 31.0f;
        float beta = 256.0f / ((1.0f - em5) * (1.0f - em5));
        for (int idx = tid; idx < TE*32; idx += 256) {
            int e = idx >> 5, j = idx & 31;
            float mean = em5 + step * j;
            float d = expf(-sR[e]) - mean;
            sRbf[e*32 + j] = sRb2[e] * expf(-beta * d * d);
        }
    }
    __syncthreads();

    // ---- phase 0c: per-l MLP -> edge weights wl --------------------------
    for (int l = 0; l < 3; ++l) {
        for (int idx = tid; idx < TE*32; idx += 256) {
            int e = idx >> 5, j = idx & 31;
            float zacc = mlp_b1[l*32 + j];
            #pragma unroll 8
            for (int rr = 0; rr < 32; ++rr) zacc += sRbf[e*32 + rr] * mlp_w1[(l*32 + rr)*32 + j];
            sH[e*32 + j] = zacc / (1.0f + expf(-zacc));   // silu
        }
        __syncthreads();
        for (int idx = tid; idx < TE*4; idx += 256) {
            int e = idx >> 2, v = idx & 3;
            float zacc = mlp_b2[l*4 + v];
            #pragma unroll 8
            for (int j = 0; j < 32; ++j) zacc += sH[e*32 + j] * mlp_w2[(l*32 + j)*4 + v];
            sWl[e][l*4 + v] = zacc;
        }
        __syncthreads();
    }
    // pack wl as f16 pairs: sWlPk[e][l*2 + vh] = (wl[l][2vh], wl[l][2vh+1])
    for (int idx = tid; idx < TE*6; idx += 256) {
        int e = idx / 6, h = idx - e*6;
        int l = h >> 1, vh = h & 1;
        f16x2 p = {(f16)sWl[e][l*4 + vh*2], (f16)sWl[e][l*4 + vh*2 + 1]};
        sWlPk[e][h] = p;
    }
    __syncthreads();

    f32x4 acc[3];

    // ---- group l3=0: N=64, NK=1, K=448 -----------------------------------
    #pragma unroll
    for (int t = 0; t < 3; ++t) acc[t] = {0.f, 0.f, 0.f, 0.f};
    path_mfma<0,0,0>(tid,     0,   0, tp_w, A_lds, W_lds, cy_lds, sN16, sY, sW3, sWlPk, acc);
    path_mfma<1,1,0>(tid, 16384,   1, tp_w, A_lds, W_lds, cy_lds, sN16, sY, sW3, sWlPk, acc);
    path_mfma<2,2,0>(tid, 24576,  10, tp_w, A_lds, W_lds, cy_lds, sN16, sY, sW3, sWlPk, acc);
    store_group<1, 4, 8, 0>(tid, acc, sAcc16);

    // ---- group l3=1: N=32, NK=3, K=576 -----------------------------------
    #pragma unroll
    for (int t = 0; t < 3; ++t) acc[t] = {0.f, 0.f, 0.f, 0.f};
    path_mfma<0,1,1>(tid, 28672,  35, tp_w, A_lds, W_lds, cy_lds, sN16, sY, sW3, sWlPk, acc);
    path_mfma<1,0,1>(tid, 36864,  44, tp_w, A_lds, W_lds, cy_lds, sN16, sY, sW3, sWlPk, acc);
    path_mfma<1,2,1>(tid, 40960,  53, tp_w, A_lds, W_lds, cy_lds, sN16, sY, sW3, sWlPk, acc);
    path_mfma<2,1,1>(tid, 45056,  98, tp_w, A_lds, W_lds, cy_lds, sN16, sY, sW3, sWlPk, acc);
    store_group<3, 2, 12, 64>(tid, acc, sAcc16);

    // ---- group l3=2: N=16, NK=5, K=512 -----------------------------------
    #pragma unroll
    for (int t = 0; t < 3; ++t) acc[t] = {0.f, 0.f, 0.f, 0.f};
    path_mfma<0,2,2>(tid, 47104, 143, tp_w, A_lds, W_lds, cy_lds, sN16, sY, sW3, sWlPk, acc);
    path_mfma<2,0,2>(tid, 51200, 168, tp_w, A_lds, W_lds, cy_lds, sN16, sY, sW3, sWlPk, acc);
    path_mfma<1,1,2>(tid, 52224, 193, tp_w, A_lds, W_lds, cy_lds, sN16, sY, sW3, sWlPk, acc);
    path_mfma<2,2,2>(tid, 54272, 238, tp_w, A_lds, W_lds, cy_lds, sN16, sY, sW3, sWlPk, acc);
    store_group<5, 1, 10, 160>(tid, acc, sAcc16);

    __syncthreads();

    // ---- single coalesced nontemporal output pass ------------------------
    {
        const float a0 = 1.0f / sqrtf(448.0f);   // channels [0,64)
        const float a1 = 1.0f / 24.0f;           // channels [64,160)
        const float a2 = 1.0f / sqrtf(512.0f);   // channels [160,240)
        for (int idx = tid; idx < TE*30; idx += 256) {
            int e = idx / 30, q = idx - e*30;    // q = half8 index within row
            float al = (q < 8) ? a0 : (q < 20) ? a1 : a2;
            float m  = al * sMask[e];
            f16x8 v = *(const f16x8*)&sAcc16[e*240 + q*8];
            f32x4 lo = {(float)v[0]*m, (float)v[1]*m, (float)v[2]*m, (float)v[3]*m};
            f32x4 hi = {(float)v[4]*m, (float)v[5]*m, (float)v[6]*m, (float)v[7]*m};
            float* dst = out + (eg0 + e)*NODE_DIM + q*8;
            __builtin_nontemporal_store(lo, (f32x4*)dst);
            __builtin_nontemporal_store(hi, (f32x4*)(dst + 4));
        }
    }
}

// ---------------------------------------------------------------------------
// launch
// ---------------------------------------------------------------------------
extern "C" void kernel_launch(void* const* d_in, const int* in_sizes, int n_in,
                              void* d_out, int out_size, void* d_ws, size_t ws_size,
                              hipStream_t stream)
{
    const float* node_feat = (const float*)d_in[0];
    const int*   edge_idx  = (const int*)  d_in[1];
    const float* edge_vec  = (const float*)d_in[2];
    const float* maskp     = (const float*)d_in[3];
    const float* mlp_w1    = (const float*)d_in[4];
    const float* mlp_b1    = (const float*)d_in[5];
    const float* mlp_w2    = (const float*)d_in[6];
    const float* mlp_b2    = (const float*)d_in[7];
    const float* tp_w      = (const float*)d_in[8];
    float* out = (float*)d_out;
    float* w3j = (float*)d_ws;

    int E = in_sizes[3];                 // = N_EDGES = 800000 (divisible by TE)
    const int* edge_src = edge_idx;      // row 0 of (2, E)

    hipLaunchKernelGGL(w3j_init, dim3(1), dim3(512), 0, stream, w3j);
    hipLaunchKernelGGL(edge_main, dim3(E / TE), dim3(256), 0, stream,
                       node_feat, edge_src, edge_vec, maskp,
                       mlp_w1, mlp_b1, mlp_w2, mlp_b2, tp_w, w3j, out);
}

// Round 7
// 2711.072 us; speedup vs baseline: 5.0798x; 1.3677x over previous
//
#include <hip/hip_runtime.h>
#include <math.h>

// ---------------------------------------------------------------------------
// Problem constants
// ---------------------------------------------------------------------------
#define TE 32          // edges per block
#define NODE_DIM 240

typedef _Float16 f16;
typedef f16 f16x2 __attribute__((ext_vector_type(2)));
typedef f16 f16x4 __attribute__((ext_vector_type(4)));
typedef f16 f16x8 __attribute__((ext_vector_type(8)));
typedef float f32x4 __attribute__((ext_vector_type(4)));

// PATHS = [(0,0,0),(1,1,0),(2,2,0),(0,1,1),(1,0,1),(1,2,1),
//          (2,1,1),(0,2,2),(2,0,2),(1,1,2),(2,2,2)]
// tp_w offsets: 0,16384,24576,28672,36864,40960,45056,47104,51200,52224,54272
// w3j offsets:  0,1,10,35,44,53,98,143,168,193,238 (total 363)

// ---------------------------------------------------------------------------
// Wigner-3j init kernel (exact port of the reference construction)
// ---------------------------------------------------------------------------
struct cplx { double re, im; };
__device__ inline cplx cmul(cplx a, cplx b) {
    return { a.re*b.re - a.im*b.im, a.re*b.im + a.im*b.re };
}

__device__ double dfact(int n) { double r = 1.0; for (int i = 2; i <= n; ++i) r *= i; return r; }

__device__ double su2_cg(int j1, int m1, int j2, int m2, int j3, int m3) {
    if (m3 != m1 + m2) return 0.0;
    int vmin = max(max(-j1 + j2 + m3, -j1 + m1), 0);
    int vmax = min(min(j2 + j3 + m1, j3 - j1 + j2), j3 + m3);
    double C = sqrt((2.0*j3 + 1.0) * dfact(j3 + j1 - j2) * dfact(j3 - j1 + j2) * dfact(j1 + j2 - j3)
                    * dfact(j3 + m3) * dfact(j3 - m3)
                    / (dfact(j1 + j2 + j3 + 1) * dfact(j1 - m1) * dfact(j1 + m1)
                       * dfact(j2 - m2) * dfact(j2 + m2)));
    double S = 0.0;
    for (int v = vmin; v <= vmax; ++v) {
        double sgn = ((v + j2 + m2) & 1) ? -1.0 : 1.0;
        S += sgn * dfact(j2 + j3 + m1 - v) * dfact(j1 - m1 + v)
             / (dfact(v) * dfact(j3 - j1 + j2 - v) * dfact(j3 + m3 - v) * dfact(v + j1 - j2 - m3));
    }
    return C * S;
}

__device__ cplx rtc(int l, int a, int b) {
    double re = 0.0, im = 0.0;
    const double inv_s2 = 0.70710678118654752440;
    int m = a - l;
    if (m < 0) {
        if (b == l - m)      re = inv_s2;
        else if (b == l + m) im = -inv_s2;
    } else if (m == 0) {
        if (b == l) re = 1.0;
    } else {
        double s = (m & 1) ? -1.0 : 1.0;
        if (b == l + m)      re = s * inv_s2;
        else if (b == l - m) im = s * inv_s2;
    }
    if (l == 1) { double t = re; re = im; im = -t; }
    else if (l == 2) { re = -re; im = -im; }
    return { re, im };
}

__global__ void w3j_init(float* __restrict__ out) {
    __shared__ double sRe[363], sIm[363];
    __shared__ double sNorm[11];
    __shared__ int    sUse[11];
    const int L1A[11] = {0,1,2,0,1,1,2,0,2,1,2};
    const int L2A[11] = {0,1,2,1,0,2,1,2,0,1,2};
    const int L3A[11] = {0,0,0,1,1,1,1,2,2,2,2};
    const int OFF[12] = {0,1,10,35,44,53,98,143,168,193,238,363};
    int t = threadIdx.x;
    if (t < 363) {
        int p = 0;
        while (p < 10 && t >= OFF[p+1]) ++p;
        int rel = t - OFF[p];
        int a1 = L1A[p], a2 = L2A[p], a3 = L3A[p];
        int n1 = 2*a1 + 1, n2 = 2*a2 + 1, n3 = 2*a3 + 1;
        int jj = rel / (n2*n3), ll = (rel / n3) % n2, mm = rel % n3;
        double cr = 0.0, ci = 0.0;
        for (int i = 0; i < n1; ++i)
            for (int k = 0; k < n2; ++k)
                for (int n = 0; n < n3; ++n) {
                    double c = su2_cg(a1, i - a1, a2, k - a2, a3, n - a3);
                    if (c == 0.0) continue;
                    cplx q1 = rtc(a1, i, jj);
                    cplx q2 = rtc(a2, k, ll);
                    cplx q3 = rtc(a3, n, mm); q3.im = -q3.im;
                    cplx pr = cmul(cmul(q1, q2), q3);
                    cr += pr.re * c; ci += pr.im * c;
                }
        sRe[t] = cr; sIm[t] = ci;
    }
    __syncthreads();
    if (t < 11) {
        double nr = 0.0, ni = 0.0;
        for (int e = OFF[t]; e < OFF[t+1]; ++e) { nr += sRe[e]*sRe[e]; ni += sIm[e]*sIm[e]; }
        int use_im = (sqrt(nr) < 1e-8) ? 1 : 0;
        sUse[t] = use_im;
        sNorm[t] = sqrt(use_im ? ni : nr);
    }
    __syncthreads();
    if (t < 363) {
        int p = 0;
        while (p < 10 && t >= OFF[p+1]) ++p;
        out[t] = (float)((sUse[p] ? sIm[t] : sRe[t]) / sNorm[p]);
    }
}

// ---------------------------------------------------------------------------
// Weight prep: tp_w (f32) -> f16, alpha folded in, laid out in per-lane
// fragment order. Per path: fragment blocks of **512** f16 (16 n x 32 k =
// one MFMA B tile = 64 lanes x 8), indexed f = (ch*KSn + ks)*NT + nt.
// Within a block, element lane*8+jj holds
//   W[k = ks*32 + (lane>>4)*8 + jj][n = nt*16 + (lane&15)]  of chunk ch
// so a wave's B-fragment load is one coalesced f16x8 per lane.
// (Round-6 bug: blocks were treated as 256 f16 with lane<32 -> garbage.)
// ---------------------------------------------------------------------------
__global__ void w_prep(const float* __restrict__ tp_w, f16* __restrict__ wpre) {
    const int WOFF[11] = {0,16384,24576,28672,36864,40960,45056,47104,51200,52224,54272};
    const int UA[11]   = {64,32,16,64,32,32,16,64,16,32,16};
    const int NA[11]   = {64,64,64,32,32,32,32,16,16,16,16};
    const int L3A[11]  = {0,0,0,1,1,1,1,2,2,2,2};
    const float alph[3] = { 1.0f/sqrtf(448.0f), 1.0f/24.0f, 1.0f/sqrtf(512.0f) };
    int tid = threadIdx.x;
    for (int p = 0; p < 11; ++p) {
        int U = UA[p], N = NA[p], woff = WOFF[p];
        int UC = (U >= 32) ? 32 : 16;
        int KC = UC*4, KSn = KC/32, NT = N/16;
        int size = U*4*N;
        float alpha = alph[L3A[p]];
        for (int j = tid; j < size; j += 256) {
            int f = j >> 9, r = j & 511;                // 512 f16 per fragment block
            int lane = r >> 3, jj = r & 7;              // lane 0..63
            int pernch = KSn*NT;
            int ch = f / pernch, rem = f - ch*pernch;
            int ks = rem / NT, nt = rem - ks*NT;
            int k = ks*32 + (lane>>4)*8 + jj;
            int n = nt*16 + (lane&15);
            int krow = ch*KC + k;                       // global (u*4+v) row
            wpre[woff + j] = (f16)(tp_w[woff + krow*N + n] * alpha);
        }
    }
}

// ---------------------------------------------------------------------------
// One path as a shared-weight GEMM on fp16 MFMA.
// A[(kk*TE+e), (u,v)] = (sum_i n[e,u,i]*cy[e,i,kk]) * (wl[e,v]*mask[e])
// W fragments come straight from wpre (global, L2-hot) into registers.
// A staged in LDS with XOR granule swizzle (conflict-optimal both sides).
// ---------------------------------------------------------------------------
template<int l1, int l2, int l3>
__device__ __forceinline__ void path_mfma(
    int tid, int woff, int cgoff,
    const f16* __restrict__ wpre,
    f16* A_lds, float* cy_lds,
    const f16* sN16, const float (*sY)[8], const float* sW3,
    const f16x2 (*sWlPk)[6],
    f32x4 (&acc)[3])
{
    constexpr int U  = (l1 == 0) ? 64 : (l1 == 1) ? 32 : 16;
    constexpr int N  = (l3 == 0) ? 64 : (l3 == 1) ? 32 : 16;
    constexpr int NI = 2*l1 + 1, NJ = 2*l2 + 1, NK = 2*l3 + 1;
    constexpr int M  = NK * TE;
    constexpr int NODE_OFF = (l1 == 0) ? 0 : (l1 == 1) ? 64 : 160;
    constexpr int UC  = (U >= 32) ? 32 : 16;     // u's per K-chunk
    constexpr int KC  = UC * 4;                  // k's per chunk (128 or 64)
    constexpr int GR  = KC / 8;                  // 16B granules per A row
    constexpr int KSn = KC / 32;                 // MFMA K-steps per chunk
    constexpr int NCH = U / UC;
    constexpr int NT  = N / 16;
    constexpr int NTASKS = (M/16) * NT;
    constexpr int URS = (UC == 32) ? 5 : 4;

    const int wv = tid >> 6, lane = tid & 63;
    const int ln = tid & 15, qt = (tid & 63) >> 4;
    const int ntw = wv % NT;                     // wave-constant n-tile

    // phase a: cy[e][i][kk] = sum_j Y[e,j] * C[i,j,kk]
    for (int idx = tid; idx < TE*NI*NK; idx += 256) {
        int e = idx / (NI*NK), rem = idx - e*(NI*NK);
        int i = rem / NK, kk = rem - i*NK;
        float c = 0.f;
        #pragma unroll
        for (int j = 0; j < NJ; ++j) {
            float yj = (l2 == 0) ? 1.f : ((l2 == 1) ? sY[e][j] : sY[e][3 + j]);
            c += sW3[cgoff + (i*NJ + j)*NK + kk] * yj;
        }
        cy_lds[idx] = c;
    }
    __syncthreads();

    for (int ch = 0; ch < NCH; ++ch) {
        // --- issue W fragment loads early (consumed after the barrier) ----
        // fragment block f = (ch*KSn + ks)*NT + ntw, 512 f16 each
        const f16* wbase = wpre + woff + (size_t)((ch*KSn)*NT + ntw)*512 + lane*8;
        f16x8 wreg[KSn];
        #pragma unroll
        for (int ks = 0; ks < KSn; ++ks)
            wreg[ks] = *(const f16x8*)(wbase + (size_t)ks*NT*512);

        // --- build A chunk [M][KC] f16, XOR-swizzled 16B granules ---------
        const int u0 = ch * UC;
        for (int idx = tid; idx < M*UC; idx += 256) {
            int row = idx >> URS, ur = idx & (UC - 1);
            int e = row & 31, kk = row >> 5;
            float b = 0.f;
            #pragma unroll
            for (int i = 0; i < NI; ++i)
                b += (float)sN16[e*240 + NODE_OFF + (u0 + ur)*NI + i]
                     * cy_lds[(e*NI + i)*NK + kk];
            f16 bh = (f16)b;
            f16x2 bb = {bh, bh};
            f16x2 a01 = bb * sWlPk[e][l2*2 + 0];
            f16x2 a23 = bb * sWlPk[e][l2*2 + 1];
            f16x4 av = {a01[0], a01[1], a23[0], a23[1]};
            int c  = ur >> 1;                            // 16B granule col
            int cs = c ^ (row & (GR - 1));               // swizzle
            *(f16x4*)&A_lds[row*KC + cs*8 + (ur & 1)*4] = av;
        }
        __syncthreads();

        // --- MFMA: wave's tasks share nt=ntw; A frags from swizzled LDS ---
        #pragma unroll
        for (int ks = 0; ks < KSn; ++ks) {
            #pragma unroll
            for (int t = 0; t < 3; ++t) {
                int task = t*4 + wv;
                if (task < NTASKS) {
                    int mt  = task / NT;
                    int row = mt*16 + ln;
                    int cs  = (ks*4 + qt) ^ (row & (GR - 1));
                    f16x8 af = *(const f16x8*)&A_lds[row*KC + cs*8];
                    acc[t] = __builtin_amdgcn_mfma_f32_16x16x32_f16(af, wreg[ks], acc[t], 0, 0, 0);
                }
            }
        }
        __syncthreads();
    }
}

// write a group's accumulators into the f16 staging tile
// D layout (verified r5): col = lane&15, row = 4*(lane>>4) + reg
template<int NK, int NT, int NTASKS, int OFF>
__device__ __forceinline__ void store_group(int tid, const f32x4 (&acc)[3], f16* sAcc16)
{
    int wv = tid >> 6;
    int ln = tid & 15, qt = (tid & 63) >> 4;
    #pragma unroll
    for (int t = 0; t < 3; ++t) {
        int task = t*4 + wv;
        if (task < NTASKS) {
            int mt = task / NT, nt = task % NT;
            int kk = mt >> 1;
            int e0 = (mt & 1) * 16;
            #pragma unroll
            for (int r = 0; r < 4; ++r) {
                int e = e0 + qt*4 + r;
                sAcc16[e*240 + OFF + (nt*16 + ln)*NK + kk] = (f16)acc[t][r];
            }
        }
    }
}

__global__ __launch_bounds__(256, 2)
void edge_main(const float* __restrict__ node_feat,
               const int*   __restrict__ edge_src,
               const float* __restrict__ edge_vec,
               const float* __restrict__ maskp,
               const float* __restrict__ mlp_w1, const float* __restrict__ mlp_b1,
               const float* __restrict__ mlp_w2, const float* __restrict__ mlp_b2,
               const f16*   __restrict__ wpre,
               const float* __restrict__ w3j,
               float* __restrict__ out)
{
    __shared__ __align__(16) f16 A_lds[160*128];    // 40KB A chunk (max M=160,KC=128)
    __shared__ __align__(16) f16 sN16[TE*240];      // 15.4KB node rows (f16)
    __shared__ __align__(16) f16 sAcc16[TE*240];    // 15.4KB result staging (f16)
    __shared__ float cy_lds[800];                   // 3.2KB
    __shared__ float sW3[364];
    __shared__ float sY[TE][8];
    __shared__ f16x2 sWlPk[TE][6];

    // phase-0 scratch aliases onto A_lds (used & done before any A build)
    float* sRbf  = (float*)A_lds;           // [TE][32]
    float* sH    = sRbf + TE*32;            // [TE][32]
    float* sWl   = sH   + TE*32;            // [TE][12]
    float* sR    = sWl  + TE*12;            // [TE]
    float* sRb2  = sR   + TE;               // [TE]
    float* sMask = sRb2 + TE;               // [TE]
    int*   sSrc  = (int*)(sMask + TE);      // [TE]

    int tid = threadIdx.x;
    long eg0 = (long)blockIdx.x * TE;

    // ---- phase 0a: per-edge geometry -------------------------------------
    if (tid < TE) {
        long eg = eg0 + tid;
        float vx = edge_vec[eg*3 + 0], vy = edge_vec[eg*3 + 1], vz = edge_vec[eg*3 + 2];
        float rn = sqrtf(vx*vx + vy*vy + vz*vz);
        float r  = fmaxf(rn, 1e-12f);
        float inv = 1.0f / r;
        float x = vx*inv, y = vy*inv, z = vz*inv;
        sR[tid] = r;
        float rb = 0.5f * (cosf(r * 3.14159265358979323846f / 5.0f) + 1.0f);
        sRb2[tid] = (r < 5.0f) ? rb*rb : 0.0f;
        sMask[tid] = maskp[eg];
        sSrc[tid]  = edge_src[eg];
        const float s3 = sqrtf(3.0f), s5 = sqrtf(5.0f), s15 = sqrtf(15.0f);
        sY[tid][0] = s3*x; sY[tid][1] = s3*y; sY[tid][2] = s3*z;
        sY[tid][3] = s15*x*z;
        sY[tid][4] = s15*x*y;
        sY[tid][5] = s5*(y*y - 0.5f*(x*x + z*z));
        sY[tid][6] = s15*y*z;
        sY[tid][7] = 0.5f*s15*(z*z - x*x);
    }
    for (int t = tid; t < 363; t += 256) sW3[t] = w3j[t];   // grid-stride (363 > 256)
    __syncthreads();

    // ---- phase 0b: gather node rows (f32 float4 -> f16 LDS) + RBF --------
    {
        float em5  = expf(-5.0f);
        float step = (1.0f - em5) / 31.0f;
        float beta = 256.0f / ((1.0f - em5) * (1.0f - em5));
        for (int idx = tid; idx < TE*32; idx += 256) {
            int e = idx >> 5, j = idx & 31;
            float mean = em5 + step * j;
            float d = expf(-sR[e]) - mean;
            sRbf[e*32 + j] = sRb2[e] * expf(-beta * d * d);
        }
    }
    for (int idx = tid; idx < TE*60; idx += 256) {
        int e = idx / 60, q = idx - e*60;
        f32x4 v = *(const f32x4*)(node_feat + (long)sSrc[e]*NODE_DIM + q*4);
        f16x4 h = {(f16)v.x, (f16)v.y, (f16)v.z, (f16)v.w};
        *(f16x4*)&sN16[e*240 + q*4] = h;
    }
    __syncthreads();

    // ---- phase 0c: per-l MLP -> edge weights wl (mask folded in) ---------
    for (int l = 0; l < 3; ++l) {
        for (int idx = tid; idx < TE*32; idx += 256) {
            int e = idx >> 5, j = idx & 31;
            float zacc = mlp_b1[l*32 + j];
            #pragma unroll 8
            for (int rr = 0; rr < 32; ++rr) zacc += sRbf[e*32 + rr] * mlp_w1[(l*32 + rr)*32 + j];
            sH[e*32 + j] = zacc / (1.0f + expf(-zacc));   // silu
        }
        __syncthreads();
        for (int idx = tid; idx < TE*4; idx += 256) {
            int e = idx >> 2, v = idx & 3;
            float zacc = mlp_b2[l*4 + v];
            #pragma unroll 8
            for (int j = 0; j < 32; ++j) zacc += sH[e*32 + j] * mlp_w2[(l*32 + j)*4 + v];
            sWl[e*12 + l*4 + v] = zacc;
        }
        __syncthreads();
    }
    // pack (wl * mask) as f16 pairs
    for (int idx = tid; idx < TE*6; idx += 256) {
        int e = idx / 6, h = idx - e*6;
        int l = h >> 1, vh = h & 1;
        float m = sMask[e];
        f16x2 p = {(f16)(sWl[e*12 + l*4 + vh*2] * m), (f16)(sWl[e*12 + l*4 + vh*2 + 1] * m)};
        sWlPk[e][h] = p;
    }
    __syncthreads();    // scratch dead from here; A_lds free for staging

    f32x4 acc[3];

    // ---- group l3=0: N=64, NK=1, K=448 -----------------------------------
    #pragma unroll
    for (int t = 0; t < 3; ++t) acc[t] = {0.f, 0.f, 0.f, 0.f};
    path_mfma<0,0,0>(tid,     0,   0, wpre, A_lds, cy_lds, sN16, sY, sW3, sWlPk, acc);
    path_mfma<1,1,0>(tid, 16384,   1, wpre, A_lds, cy_lds, sN16, sY, sW3, sWlPk, acc);
    path_mfma<2,2,0>(tid, 24576,  10, wpre, A_lds, cy_lds, sN16, sY, sW3, sWlPk, acc);
    store_group<1, 4, 8, 0>(tid, acc, sAcc16);

    // ---- group l3=1: N=32, NK=3, K=576 -----------------------------------
    #pragma unroll
    for (int t = 0; t < 3; ++t) acc[t] = {0.f, 0.f, 0.f, 0.f};
    path_mfma<0,1,1>(tid, 28672,  35, wpre, A_lds, cy_lds, sN16, sY, sW3, sWlPk, acc);
    path_mfma<1,0,1>(tid, 36864,  44, wpre, A_lds, cy_lds, sN16, sY, sW3, sWlPk, acc);
    path_mfma<1,2,1>(tid, 40960,  53, wpre, A_lds, cy_lds, sN16, sY, sW3, sWlPk, acc);
    path_mfma<2,1,1>(tid, 45056,  98, wpre, A_lds, cy_lds, sN16, sY, sW3, sWlPk, acc);
    store_group<3, 2, 12, 64>(tid, acc, sAcc16);

    // ---- group l3=2: N=16, NK=5, K=512 -----------------------------------
    #pragma unroll
    for (int t = 0; t < 3; ++t) acc[t] = {0.f, 0.f, 0.f, 0.f};
    path_mfma<0,2,2>(tid, 47104, 143, wpre, A_lds, cy_lds, sN16, sY, sW3, sWlPk, acc);
    path_mfma<2,0,2>(tid, 51200, 168, wpre, A_lds, cy_lds, sN16, sY, sW3, sWlPk, acc);
    path_mfma<1,1,2>(tid, 52224, 193, wpre, A_lds, cy_lds, sN16, sY, sW3, sWlPk, acc);
    path_mfma<2,2,2>(tid, 54272, 238, wpre, A_lds, cy_lds, sN16, sY, sW3, sWlPk, acc);
    store_group<5, 1, 10, 160>(tid, acc, sAcc16);

    __syncthreads();

    // ---- single coalesced nontemporal output pass (alpha/mask pre-folded) -
    for (int idx = tid; idx < TE*30; idx += 256) {
        int e = idx / 30, q = idx - e*30;        // q = half8 index within row
        f16x8 v = *(const f16x8*)&sAcc16[e*240 + q*8];
        f32x4 lo = {(float)v[0], (float)v[1], (float)v[2], (float)v[3]};
        f32x4 hi = {(float)v[4], (float)v[5], (float)v[6], (float)v[7]};
        float* dst = out + (eg0 + e)*NODE_DIM + q*8;
        __builtin_nontemporal_store(lo, (f32x4*)dst);
        __builtin_nontemporal_store(hi, (f32x4*)(dst + 4));
    }
}

// ---------------------------------------------------------------------------
// launch
// ---------------------------------------------------------------------------
extern "C" void kernel_launch(void* const* d_in, const int* in_sizes, int n_in,
                              void* d_out, int out_size, void* d_ws, size_t ws_size,
                              hipStream_t stream)
{
    const float* node_feat = (const float*)d_in[0];
    const int*   edge_idx  = (const int*)  d_in[1];
    const float* edge_vec  = (const float*)d_in[2];
    const float* maskp     = (const float*)d_in[3];
    const float* mlp_w1    = (const float*)d_in[4];
    const float* mlp_b1    = (const float*)d_in[5];
    const float* mlp_w2    = (const float*)d_in[6];
    const float* mlp_b2    = (const float*)d_in[7];
    const float* tp_w      = (const float*)d_in[8];
    float* out  = (float*)d_out;
    float* w3j  = (float*)d_ws;
    f16*   wpre = (f16*)((char*)d_ws + 2048);     // 110592 B of f16 weights

    int E = in_sizes[3];                 // = N_EDGES = 800000 (divisible by TE)
    const int* edge_src = edge_idx;      // row 0 of (2, E)

    hipLaunchKernelGGL(w3j_init, dim3(1), dim3(512), 0, stream, w3j);
    hipLaunchKernelGGL(w_prep,   dim3(1), dim3(256), 0, stream, tp_w, wpre);
    hipLaunchKernelGGL(edge_main, dim3(E / TE), dim3(256), 0, stream,
                       node_feat, edge_src, edge_vec, maskp,
                       mlp_w1, mlp_b1, mlp_w2, mlp_b2, wpre, w3j, out);
}

// Round 8
// 1173.054 us; speedup vs baseline: 11.7400x; 2.3111x over previous
//
#include <hip/hip_runtime.h>
#include <math.h>

// ---------------------------------------------------------------------------
// Problem constants
// ---------------------------------------------------------------------------
#define TE 32          // edges per block
#define NODE_DIM 240
#define NPAD 248       // f16 row stride of sN16 (496B -> 2-way banks for ln-strided reads)

typedef _Float16 f16;
typedef f16 f16x2 __attribute__((ext_vector_type(2)));
typedef f16 f16x4 __attribute__((ext_vector_type(4)));
typedef f16 f16x8 __attribute__((ext_vector_type(8)));
typedef float f32x4 __attribute__((ext_vector_type(4)));

// PATHS = [(0,0,0),(1,1,0),(2,2,0),(0,1,1),(1,0,1),(1,2,1),
//          (2,1,1),(0,2,2),(2,0,2),(1,1,2),(2,2,2)]
// tp_w offsets: 0,16384,24576,28672,36864,40960,45056,47104,51200,52224,54272
// w3j offsets:  0,1,10,35,44,53,98,143,168,193,238 (total 363)

// ---------------------------------------------------------------------------
// Wigner-3j init kernel (exact port of the reference construction)
// ---------------------------------------------------------------------------
struct cplx { double re, im; };
__device__ inline cplx cmul(cplx a, cplx b) {
    return { a.re*b.re - a.im*b.im, a.re*b.im + a.im*b.re };
}

__device__ double dfact(int n) { double r = 1.0; for (int i = 2; i <= n; ++i) r *= i; return r; }

__device__ double su2_cg(int j1, int m1, int j2, int m2, int j3, int m3) {
    if (m3 != m1 + m2) return 0.0;
    int vmin = max(max(-j1 + j2 + m3, -j1 + m1), 0);
    int vmax = min(min(j2 + j3 + m1, j3 - j1 + j2), j3 + m3);
    double C = sqrt((2.0*j3 + 1.0) * dfact(j3 + j1 - j2) * dfact(j3 - j1 + j2) * dfact(j1 + j2 - j3)
                    * dfact(j3 + m3) * dfact(j3 - m3)
                    / (dfact(j1 + j2 + j3 + 1) * dfact(j1 - m1) * dfact(j1 + m1)
                       * dfact(j2 - m2) * dfact(j2 + m2)));
    double S = 0.0;
    for (int v = vmin; v <= vmax; ++v) {
        double sgn = ((v + j2 + m2) & 1) ? -1.0 : 1.0;
        S += sgn * dfact(j2 + j3 + m1 - v) * dfact(j1 - m1 + v)
             / (dfact(v) * dfact(j3 - j1 + j2 - v) * dfact(j3 + m3 - v) * dfact(v + j1 - j2 - m3));
    }
    return C * S;
}

__device__ cplx rtc(int l, int a, int b) {
    double re = 0.0, im = 0.0;
    const double inv_s2 = 0.70710678118654752440;
    int m = a - l;
    if (m < 0) {
        if (b == l - m)      re = inv_s2;
        else if (b == l + m) im = -inv_s2;
    } else if (m == 0) {
        if (b == l) re = 1.0;
    } else {
        double s = (m & 1) ? -1.0 : 1.0;
        if (b == l + m)      re = s * inv_s2;
        else if (b == l - m) im = s * inv_s2;
    }
    if (l == 1) { double t = re; re = im; im = -t; }
    else if (l == 2) { re = -re; im = -im; }
    return { re, im };
}

__global__ void w3j_init(float* __restrict__ out) {
    __shared__ double sRe[363], sIm[363];
    __shared__ double sNorm[11];
    __shared__ int    sUse[11];
    const int L1A[11] = {0,1,2,0,1,1,2,0,2,1,2};
    const int L2A[11] = {0,1,2,1,0,2,1,2,0,1,2};
    const int L3A[11] = {0,0,0,1,1,1,1,2,2,2,2};
    const int OFF[12] = {0,1,10,35,44,53,98,143,168,193,238,363};
    int t = threadIdx.x;
    if (t < 363) {
        int p = 0;
        while (p < 10 && t >= OFF[p+1]) ++p;
        int rel = t - OFF[p];
        int a1 = L1A[p], a2 = L2A[p], a3 = L3A[p];
        int n1 = 2*a1 + 1, n2 = 2*a2 + 1, n3 = 2*a3 + 1;
        int jj = rel / (n2*n3), ll = (rel / n3) % n2, mm = rel % n3;
        double cr = 0.0, ci = 0.0;
        for (int i = 0; i < n1; ++i)
            for (int k = 0; k < n2; ++k)
                for (int n = 0; n < n3; ++n) {
                    double c = su2_cg(a1, i - a1, a2, k - a2, a3, n - a3);
                    if (c == 0.0) continue;
                    cplx q1 = rtc(a1, i, jj);
                    cplx q2 = rtc(a2, k, ll);
                    cplx q3 = rtc(a3, n, mm); q3.im = -q3.im;
                    cplx pr = cmul(cmul(q1, q2), q3);
                    cr += pr.re * c; ci += pr.im * c;
                }
        sRe[t] = cr; sIm[t] = ci;
    }
    __syncthreads();
    if (t < 11) {
        double nr = 0.0, ni = 0.0;
        for (int e = OFF[t]; e < OFF[t+1]; ++e) { nr += sRe[e]*sRe[e]; ni += sIm[e]*sIm[e]; }
        int use_im = (sqrt(nr) < 1e-8) ? 1 : 0;
        sUse[t] = use_im;
        sNorm[t] = sqrt(use_im ? ni : nr);
    }
    __syncthreads();
    if (t < 363) {
        int p = 0;
        while (p < 10 && t >= OFF[p+1]) ++p;
        out[t] = (float)((sUse[p] ? sIm[t] : sRe[t]) / sNorm[p]);
    }
}

// ---------------------------------------------------------------------------
// Weight prep (verified r7): tp_w (f32) -> f16, alpha folded, per-lane
// fragment order. Fragment blocks of 512 f16 (one 32k x 16n MFMA B tile),
// f = ks*NT + nt over the FULL K (flattened chunks); element lane*8+jj =
// W[k = ks*32 + (lane>>4)*8 + jj][n = nt*16 + (lane&15)].
// ---------------------------------------------------------------------------
__global__ void w_prep(const float* __restrict__ tp_w, f16* __restrict__ wpre) {
    const int WOFF[11] = {0,16384,24576,28672,36864,40960,45056,47104,51200,52224,54272};
    const int UA[11]   = {64,32,16,64,32,32,16,64,16,32,16};
    const int NA[11]   = {64,64,64,32,32,32,32,16,16,16,16};
    const int L3A[11]  = {0,0,0,1,1,1,1,2,2,2,2};
    const float alph[3] = { 1.0f/sqrtf(448.0f), 1.0f/24.0f, 1.0f/sqrtf(512.0f) };
    int tid = threadIdx.x;
    for (int p = 0; p < 11; ++p) {
        int U = UA[p], N = NA[p], woff = WOFF[p];
        int NT = N/16;
        int size = U*4*N;
        float alpha = alph[L3A[p]];
        for (int j = tid; j < size; j += 256) {
            int f = j >> 9, r = j & 511;                // 512 f16 per fragment block
            int lane = r >> 3, jj = r & 7;              // lane 0..63
            int ks = f / NT, nt = f - ks*NT;
            int k = ks*32 + (lane>>4)*8 + jj;           // global (u*4+v) row
            int n = nt*16 + (lane&15);
            wpre[woff + j] = (f16)(tp_w[woff + k*N + n] * alpha);
        }
    }
}

// ---------------------------------------------------------------------------
// One path, fully in registers (no LDS staging, no barriers).
// Lane (qt,ln) of wave task (mt,nt) computes its own A fragment:
//   row = mt*16+ln -> e = row&31, kk = row>>5
//   k = ks*32 + qt*8 + j -> u = ks*8 + qt*2 + (j>>2), v = j&3
//   A = (sum_i n[e, u*NI+i] * cy[e,i,kk]) * (wl[e,v]*mask[e])
// W fragments straight from wpre (L2-hot) into registers.
// ---------------------------------------------------------------------------
template<int l1, int l2, int l3>
__device__ __forceinline__ void path_mfma(
    int tid, int woff, int cgoff,
    const f16* __restrict__ wpre,
    const f16* sN16, const float (*sY)[8], const float* sW3,
    const f16x2 (*sWlPk)[6],
    f32x4 (&acc)[3])
{
    constexpr int U  = (l1 == 0) ? 64 : (l1 == 1) ? 32 : 16;
    constexpr int N  = (l3 == 0) ? 64 : (l3 == 1) ? 32 : 16;
    constexpr int NI = 2*l1 + 1, NJ = 2*l2 + 1, NK = 2*l3 + 1;
    constexpr int M  = NK * TE;
    constexpr int NODE_OFF = (l1 == 0) ? 0 : (l1 == 1) ? 64 : 160;
    constexpr int KS = U / 8;                    // MFMA K-steps (K = 4U)
    constexpr int NT = N / 16;
    constexpr int NTASKS = (M/16) * NT;

    const int wv = tid >> 6, lane = tid & 63;
    const int ln = tid & 15, qt = (tid & 63) >> 4;

    #pragma unroll
    for (int t = 0; t < 3; ++t) {
        int task = t*4 + wv;
        if (task < NTASKS) {
            int mt = task / NT, nt = task - mt*NT;
            int row = mt*16 + ln;
            int e = row & 31, kk = row >> 5;
            // cy in registers
            float cyr[NI];
            #pragma unroll
            for (int i = 0; i < NI; ++i) {
                float c = 0.f;
                #pragma unroll
                for (int j = 0; j < NJ; ++j) {
                    float yj = (l2 == 0) ? 1.f : ((l2 == 1) ? sY[e][j] : sY[e][3 + j]);
                    c += sW3[cgoff + (i*NJ + j)*NK + kk] * yj;
                }
                cyr[i] = c;
            }
            f16x2 wl0 = sWlPk[e][l2*2 + 0];
            f16x2 wl1 = sWlPk[e][l2*2 + 1];
            const f16* nbase = sN16 + e*NPAD + NODE_OFF;
            const f16* wbase = wpre + woff + (size_t)nt*512 + lane*8;
            #pragma unroll
            for (int ks = 0; ks < KS; ++ks) {
                f16x8 wf = *(const f16x8*)(wbase + (size_t)ks*NT*512);
                int u0 = ks*8 + qt*2;
                float b0 = 0.f, b1 = 0.f;
                #pragma unroll
                for (int i = 0; i < NI; ++i) {
                    b0 += (float)nbase[u0*NI + i]      * cyr[i];
                    b1 += (float)nbase[u0*NI + NI + i] * cyr[i];
                }
                f16 b0h = (f16)b0, b1h = (f16)b1;
                f16x2 bb0 = {b0h, b0h}, bb1 = {b1h, b1h};
                f16x2 a01 = bb0*wl0, a23 = bb0*wl1, a45 = bb1*wl0, a67 = bb1*wl1;
                f16x8 af = {a01[0],a01[1],a23[0],a23[1],a45[0],a45[1],a67[0],a67[1]};
                acc[t] = __builtin_amdgcn_mfma_f32_16x16x32_f16(af, wf, acc[t], 0, 0, 0);
            }
        }
    }
}

// write a group's accumulators into the f16 staging tile
// D layout (verified r5/r7): col = lane&15, row = 4*(lane>>4) + reg
template<int NK, int NT, int NTASKS, int OFF>
__device__ __forceinline__ void store_group(int tid, const f32x4 (&acc)[3], f16* sAcc16)
{
    int wv = tid >> 6;
    int ln = tid & 15, qt = (tid & 63) >> 4;
    #pragma unroll
    for (int t = 0; t < 3; ++t) {
        int task = t*4 + wv;
        if (task < NTASKS) {
            int mt = task / NT, nt = task % NT;
            int kk = mt >> 1;
            int e0 = (mt & 1) * 16;
            #pragma unroll
            for (int r = 0; r < 4; ++r) {
                int e = e0 + qt*4 + r;
                sAcc16[e*240 + OFF + (nt*16 + ln)*NK + kk] = (f16)acc[t][r];
            }
        }
    }
}

__global__ __launch_bounds__(256, 4)
void edge_main(const float* __restrict__ node_feat,
               const int*   __restrict__ edge_src,
               const float* __restrict__ edge_vec,
               const float* __restrict__ maskp,
               const float* __restrict__ mlp_w1, const float* __restrict__ mlp_b1,
               const float* __restrict__ mlp_w2, const float* __restrict__ mlp_b2,
               const f16*   __restrict__ wpre,
               const float* __restrict__ w3j,
               float* __restrict__ out)
{
    __shared__ __align__(16) f16 sN16[TE*NPAD];     // 15.9KB node rows (padded)
    __shared__ __align__(16) f16 sAcc16[TE*240];    // 15.4KB result staging
    __shared__ float sW3[364];
    __shared__ float sY[TE][8];
    __shared__ f16x2 sWlPk[TE][6];

    // phase-0 scratch aliases onto sAcc16 (10.1KB used; dead before store_group)
    float* sRbf  = (float*)sAcc16;          // [TE][32]  4KB
    float* sH    = sRbf + TE*32;            // [TE][32]  4KB
    float* sWl   = sH   + TE*32;            // [TE][12]  1.5KB
    float* sR    = sWl  + TE*12;            // [TE]
    float* sRb2  = sR   + TE;               // [TE]
    float* sMask = sRb2 + TE;               // [TE]
    int*   sSrc  = (int*)(sMask + TE);      // [TE]

    int tid = threadIdx.x;
    long eg0 = (long)blockIdx.x * TE;

    // ---- phase 0a: per-edge geometry -------------------------------------
    if (tid < TE) {
        long eg = eg0 + tid;
        float vx = edge_vec[eg*3 + 0], vy = edge_vec[eg*3 + 1], vz = edge_vec[eg*3 + 2];
        float rn = sqrtf(vx*vx + vy*vy + vz*vz);
        float r  = fmaxf(rn, 1e-12f);
        float inv = 1.0f / r;
        float x = vx*inv, y = vy*inv, z = vz*inv;
        sR[tid] = r;
        float rb = 0.5f * (cosf(r * 3.14159265358979323846f / 5.0f) + 1.0f);
        sRb2[tid] = (r < 5.0f) ? rb*rb : 0.0f;
        sMask[tid] = maskp[eg];
        sSrc[tid]  = edge_src[eg];
        const float s3 = sqrtf(3.0f), s5 = sqrtf(5.0f), s15 = sqrtf(15.0f);
        sY[tid][0] = s3*x; sY[tid][1] = s3*y; sY[tid][2] = s3*z;
        sY[tid][3] = s15*x*z;
        sY[tid][4] = s15*x*y;
        sY[tid][5] = s5*(y*y - 0.5f*(x*x + z*z));
        sY[tid][6] = s15*y*z;
        sY[tid][7] = 0.5f*s15*(z*z - x*x);
    }
    for (int t = tid; t < 363; t += 256) sW3[t] = w3j[t];   // grid-stride (363 > 256)
    __syncthreads();

    // ---- phase 0b: gather node rows (f32 float4 -> f16 LDS) + RBF --------
    {
        float em5  = expf(-5.0f);
        float step = (1.0f - em5) / 31.0f;
        float beta = 256.0f / ((1.0f - em5) * (1.0f - em5));
        for (int idx = tid; idx < TE*32; idx += 256) {
            int e = idx >> 5, j = idx & 31;
            float mean = em5 + step * j;
            float d = expf(-sR[e]) - mean;
            sRbf[e*32 + j] = sRb2[e] * expf(-beta * d * d);
        }
    }
    for (int idx = tid; idx < TE*60; idx += 256) {
        int e = idx / 60, q = idx - e*60;
        f32x4 v = *(const f32x4*)(node_feat + (long)sSrc[e]*NODE_DIM + q*4);
        f16x4 h = {(f16)v.x, (f16)v.y, (f16)v.z, (f16)v.w};
        *(f16x4*)&sN16[e*NPAD + q*4] = h;
    }
    __syncthreads();

    // ---- phase 0c: per-l MLP -> edge weights wl (mask folded in) ---------
    for (int l = 0; l < 3; ++l) {
        for (int idx = tid; idx < TE*32; idx += 256) {
            int e = idx >> 5, j = idx & 31;
            float zacc = mlp_b1[l*32 + j];
            #pragma unroll 8
            for (int rr = 0; rr < 32; ++rr) zacc += sRbf[e*32 + rr] * mlp_w1[(l*32 + rr)*32 + j];
            sH[e*32 + j] = zacc / (1.0f + expf(-zacc));   // silu
        }
        __syncthreads();
        for (int idx = tid; idx < TE*4; idx += 256) {
            int e = idx >> 2, v = idx & 3;
            float zacc = mlp_b2[l*4 + v];
            #pragma unroll 8
            for (int j = 0; j < 32; ++j) zacc += sH[e*32 + j] * mlp_w2[(l*32 + j)*4 + v];
            sWl[e*12 + l*4 + v] = zacc;
        }
        __syncthreads();
    }
    // pack (wl * mask) as f16 pairs
    for (int idx = tid; idx < TE*6; idx += 256) {
        int e = idx / 6, h = idx - e*6;
        int l = h >> 1, vh = h & 1;
        float m = sMask[e];
        f16x2 p = {(f16)(sWl[e*12 + l*4 + vh*2] * m), (f16)(sWl[e*12 + l*4 + vh*2 + 1] * m)};
        sWlPk[e][h] = p;
    }
    __syncthreads();    // scratch (aliased on sAcc16) dead from here

    f32x4 acc[3];

    // ---- group l3=0: N=64, NK=1, K=448 (no barriers inside) --------------
    #pragma unroll
    for (int t = 0; t < 3; ++t) acc[t] = {0.f, 0.f, 0.f, 0.f};
    path_mfma<0,0,0>(tid,     0,   0, wpre, sN16, sY, sW3, sWlPk, acc);
    path_mfma<1,1,0>(tid, 16384,   1, wpre, sN16, sY, sW3, sWlPk, acc);
    path_mfma<2,2,0>(tid, 24576,  10, wpre, sN16, sY, sW3, sWlPk, acc);
    store_group<1, 4, 8, 0>(tid, acc, sAcc16);

    // ---- group l3=1: N=32, NK=3, K=576 -----------------------------------
    #pragma unroll
    for (int t = 0; t < 3; ++t) acc[t] = {0.f, 0.f, 0.f, 0.f};
    path_mfma<0,1,1>(tid, 28672,  35, wpre, sN16, sY, sW3, sWlPk, acc);
    path_mfma<1,0,1>(tid, 36864,  44, wpre, sN16, sY, sW3, sWlPk, acc);
    path_mfma<1,2,1>(tid, 40960,  53, wpre, sN16, sY, sW3, sWlPk, acc);
    path_mfma<2,1,1>(tid, 45056,  98, wpre, sN16, sY, sW3, sWlPk, acc);
    store_group<3, 2, 12, 64>(tid, acc, sAcc16);

    // ---- group l3=2: N=16, NK=5, K=512 -----------------------------------
    #pragma unroll
    for (int t = 0; t < 3; ++t) acc[t] = {0.f, 0.f, 0.f, 0.f};
    path_mfma<0,2,2>(tid, 47104, 143, wpre, sN16, sY, sW3, sWlPk, acc);
    path_mfma<2,0,2>(tid, 51200, 168, wpre, sN16, sY, sW3, sWlPk, acc);
    path_mfma<1,1,2>(tid, 52224, 193, wpre, sN16, sY, sW3, sWlPk, acc);
    path_mfma<2,2,2>(tid, 54272, 238, wpre, sN16, sY, sW3, sWlPk, acc);
    store_group<5, 1, 10, 160>(tid, acc, sAcc16);

    __syncthreads();

    // ---- single coalesced nontemporal output pass (alpha/mask pre-folded) -
    for (int idx = tid; idx < TE*30; idx += 256) {
        int e = idx / 30, q = idx - e*30;        // q = half8 index within row
        f16x8 v = *(const f16x8*)&sAcc16[e*240 + q*8];
        f32x4 lo = {(float)v[0], (float)v[1], (float)v[2], (float)v[3]};
        f32x4 hi = {(float)v[4], (float)v[5], (float)v[6], (float)v[7]};
        float* dst = out + (eg0 + e)*NODE_DIM + q*8;
        __builtin_nontemporal_store(lo, (f32x4*)dst);
        __builtin_nontemporal_store(hi, (f32x4*)(dst + 4));
    }
}

// ---------------------------------------------------------------------------
// launch
// ---------------------------------------------------------------------------
extern "C" void kernel_launch(void* const* d_in, const int* in_sizes, int n_in,
                              void* d_out, int out_size, void* d_ws, size_t ws_size,
                              hipStream_t stream)
{
    const float* node_feat = (const float*)d_in[0];
    const int*   edge_idx  = (const int*)  d_in[1];
    const float* edge_vec  = (const float*)d_in[2];
    const float* maskp     = (const float*)d_in[3];
    const float* mlp_w1    = (const float*)d_in[4];
    const float* mlp_b1    = (const float*)d_in[5];
    const float* mlp_w2    = (const float*)d_in[6];
    const float* mlp_b2    = (const float*)d_in[7];
    const float* tp_w      = (const float*)d_in[8];
    float* out  = (float*)d_out;
    float* w3j  = (float*)d_ws;
    f16*   wpre = (f16*)((char*)d_ws + 2048);     // 110592 B of f16 weights

    int E = in_sizes[3];                 // = N_EDGES = 800000 (divisible by TE)
    const int* edge_src = edge_idx;      // row 0 of (2, E)

    hipLaunchKernelGGL(w3j_init, dim3(1), dim3(512), 0, stream, w3j);
    hipLaunchKernelGGL(w_prep,   dim3(1), dim3(256), 0, stream, tp_w, wpre);
    hipLaunchKernelGGL(edge_main, dim3(E / TE), dim3(256), 0, stream,
                       node_feat, edge_src, edge_vec, maskp,
                       mlp_w1, mlp_b1, mlp_w2, mlp_b2, wpre, w3j, out);
}